// Round 9
// baseline (1111.182 us; speedup 1.0000x reference)
//
#include <hip/hip_runtime.h>
#include <hip/hip_bf16.h>
#include <math.h>

#define N_NODES 50000
#define D_FEAT  128
#define HIDDEN  256
#define CLASSES 40
#define N_EDGES 800000
#define P2S 64   // p2 row stride (u16) -> 128B rows, gathered as 32 u32/row
#define R2S 48   // r2 row stride (f32)
#define HLS 264  // h LDS row stride in u16 (256 + 8 pad)
#define ALS 136  // A-tile LDS row stride in u16 (128 + 8 pad, keeps 16B align)
#define NTILES 3125  // 50000 / 16
#define GRID_L 512   // layer grid (2 blocks/CU at 8 waves/CU)
#define NBUCK 196    // dst buckets: bucket = dst >> 8 (256-node ranges)
#define BCAP  5120   // entries per bucket (mean 4096, sigma ~64)
#define BA_BLOCKS 784  // edge-scatter blocks: 784*1024 = 802816 >= N_EDGES
#define GRID_MEGA 1536  // 6 blocks/CU x 256 CU -> all co-resident (barrier-safe)
#define CVT_CHUNKS 6586 // 6250 x-chunks + 336 weight chunks
#define NGRP 12500      // gather node-groups (4 nodes each)

typedef unsigned int  u32;
typedef unsigned short u16;
typedef __attribute__((ext_vector_type(8))) short short8;
typedef __attribute__((ext_vector_type(4))) float floatx4;

__device__ __forceinline__ float bf_lo(u32 w) { union { u32 i; float f; } u; u.i = w << 16; return u.f; }
__device__ __forceinline__ float bf_hi(u32 w) { union { u32 i; float f; } u; u.i = w & 0xffff0000u; return u.f; }
__device__ __forceinline__ float bf1(u16 h)   { union { u32 i; float f; } u; u.i = ((u32)h) << 16; return u.f; }
__device__ __forceinline__ u16 f2bf(float f) {
  union { float f; u32 i; } u; u.f = f; u32 i = u.i;
  return (u16)((i + 0x7fffu + ((i >> 16) & 1u)) >> 16);  // RNE
}
__device__ __forceinline__ u32 packbf(float a, float b) { return (u32)f2bf(a) | ((u32)f2bf(b) << 16); }

// Per-block edge-dtype probe: 8 fixed samples, identical for every block.
__device__ __forceinline__ bool edges_are_i64(const void* eraw) {
  const long long* p = (const long long*)eraw;
  bool ok = true;
  #pragma unroll
  for (int i = 0; i < 8; i++) {
    long long v = p[(size_t)i * 100003];
    ok = ok && (v >= 0) && (v < N_NODES);
  }
  return ok;
}

// Hand-rolled grid barrier (NORMAL launch; all blocks co-resident by
// construction). Device-scope release/acquire per Guideline 16.
__device__ __forceinline__ void gridbar(int* cnt, int target) {
  __syncthreads();
  __threadfence();                                   // release prior writes
  if (threadIdx.x == 0) {
    __hip_atomic_fetch_add(cnt, 1, __ATOMIC_ACQ_REL, __HIP_MEMORY_SCOPE_AGENT);
    while (__hip_atomic_load(cnt, __ATOMIC_ACQUIRE, __HIP_MEMORY_SCOPE_AGENT) < target)
      __builtin_amdgcn_s_sleep(2);
  }
  __syncthreads();
  __threadfence();                                   // acquire for all threads
}

// ---- mega: scatter||cvt -> bucketBC -> gather1, one NORMAL dispatch --------
// zctl: [0..195]=bcur, [200..201]=barrier counters, [204]=cvt chunk counter.
__global__ __launch_bounds__(256, 6) void mega_kernel(
    const float* __restrict__ x,
    const float* __restrict__ Wl1, const float* __restrict__ Wr1,
    const float* __restrict__ Wl2, const float* __restrict__ Wr2,
    u16* __restrict__ xb, u16* __restrict__ wb,
    const void* __restrict__ eraw, int* __restrict__ zctl,
    u32* __restrict__ bbuf, int* __restrict__ offsets, int* __restrict__ csr,
    u16* __restrict__ agg1) {
  __shared__ int hist[NBUCK], base[NBUCK], loc[NBUCK];
  __shared__ int cnt[256], lds[256];
  __shared__ int chunk;
  const int t = threadIdx.x;
  const int b = blockIdx.x;
  int* bcur     = zctl;
  int* barcnt   = zctl + 200;
  int* cvt_next = zctl + 204;

  // ---- phase A1: edge scatter (blocks < 784), R2-verified body ------------
  if (b < BA_BLOCKS) {
    const bool i64f = edges_are_i64(eraw);
    for (int i = t; i < NBUCK; i += 256) { hist[i] = 0; loc[i] = 0; }
    __syncthreads();
    int sreg[4], dreg[4];
    const int e0 = b * 1024;
    #pragma unroll
    for (int j = 0; j < 4; j++) {
      int e = e0 + j * 256 + t;  // coalesced
      int ss = 0, dd = -1;
      if (e < N_EDGES) {
        if (i64f) {
          const long long* p = (const long long*)eraw;
          ss = (int)p[e]; dd = (int)p[N_EDGES + e];
        } else {
          const int* p = (const int*)eraw;
          ss = p[e]; dd = p[N_EDGES + e];
        }
        if ((u32)ss >= N_NODES || (u32)dd >= N_NODES) dd = -1;
      }
      sreg[j] = ss; dreg[j] = dd;
      if (dd >= 0) atomicAdd(&hist[dd >> 8], 1);
    }
    __syncthreads();
    for (int i = t; i < NBUCK; i += 256)
      base[i] = atomicAdd(&bcur[i], hist[i]);
    __syncthreads();
    #pragma unroll
    for (int j = 0; j < 4; j++) {
      int dd = dreg[j];
      if (dd >= 0) {
        int bk = dd >> 8;
        int pos = base[bk] + atomicAdd(&loc[bk], 1);
        if (pos < BCAP)
          bbuf[(size_t)bk * BCAP + pos] = (u32)sreg[j] | ((u32)(dd & 255) << 16);
      }
    }
  }

  // ---- phase A2: work-stolen f32->bf16 conversion chunks (all blocks) -----
  for (;;) {
    if (t == 0) chunk = atomicAdd(cvt_next, 1);
    __syncthreads();
    const int blk = chunk;
    __syncthreads();
    if (blk >= CVT_CHUNKS) break;
    if (blk < 6250) {
      int i = (blk * 256 + t) * 4;
      floatx4 v = *(const floatx4*)(x + i);
      u32* o = (u32*)(xb + i);
      o[0] = packbf(v.x, v.y);
      o[1] = packbf(v.z, v.w);
    } else {
      int i = (blk - 6250) * 256 + t;
      if (i < 32768)      wb[i] = f2bf(Wl1[i]);
      else if (i < 65536) wb[i] = f2bf(Wr1[i - 32768]);
      else if (i < 75776) wb[i] = f2bf(Wl2[i - 65536]);
      else if (i < 86016) wb[i] = f2bf(Wr2[i - 75776]);
    }
  }
  gridbar(barcnt, GRID_MEGA);

  // ---- phase B: fused bscan + scan2 + bucketB (blocks < 196, R3 body) -----
  if (b < NBUCK) {
    int c196 = (t < NBUCK) ? min(bcur[t], BCAP) : 0;
    lds[t] = c196;
    __syncthreads();
    #pragma unroll
    for (int d = 1; d < 256; d <<= 1) {
      int v = (t >= d) ? lds[t - d] : 0;
      __syncthreads();
      lds[t] += v;
      __syncthreads();
    }
    const int btop = (b > 0) ? lds[b - 1] : 0;
    if (b == NBUCK - 1 && t == 0) offsets[N_NODES] = lds[NBUCK - 1];
    cnt[t] = 0;
    __syncthreads();
    const int n = min(bcur[b], BCAP);
    for (int i = t; i < n; i += 256) {
      u32 e = bbuf[(size_t)b * BCAP + i];
      atomicAdd(&cnt[(e >> 16) & 255], 1);
    }
    __syncthreads();
    int c = cnt[t];
    lds[t] = c;
    __syncthreads();
    #pragma unroll
    for (int d = 1; d < 256; d <<= 1) {
      int v = (t >= d) ? lds[t - d] : 0;
      __syncthreads();
      lds[t] += v;
      __syncthreads();
    }
    const int node = b * 256 + t;
    const int off = lds[t] - c + btop;
    if (node < N_NODES) offsets[node] = off;
    cnt[t] = off;
    __syncthreads();
    for (int i = t; i < n; i += 256) {
      u32 e = bbuf[(size_t)b * BCAP + i];
      int dl = (e >> 16) & 255;
      int pos = atomicAdd(&cnt[dl], 1);
      csr[pos] = (int)(e & 0xFFFFu);
    }
  }
  gridbar(barcnt + 1, GRID_MEGA);

  // ---- phase C: layer-1 mean aggregation (all blocks, R8-verified body) ---
  {
    const int wave = t >> 6;
    const int lane = t & 63;
    for (int g = b; g < NGRP; g += GRID_MEGA) {
      const int node = g * 4 + wave;
      int bo = offsets[node], e = offsets[node + 1];
      float a0 = 0.f, a1 = 0.f, b0 = 0.f, b1 = 0.f;
      float c0 = 0.f, c1 = 0.f, d0 = 0.f, d1 = 0.f;
      float e0 = 0.f, e1 = 0.f, f0 = 0.f, f1 = 0.f;
      float g0 = 0.f, g1 = 0.f, h0 = 0.f, h1 = 0.f;
      int i = bo;
      for (; i + 8 <= e; i += 8) {
        int s0 = csr[i],     s1 = csr[i + 1], s2 = csr[i + 2], s3 = csr[i + 3];
        int s4 = csr[i + 4], s5 = csr[i + 5], s6 = csr[i + 6], s7 = csr[i + 7];
        u32 w0 = ((const u32*)(xb + (size_t)s0 * D_FEAT))[lane];
        u32 w1 = ((const u32*)(xb + (size_t)s1 * D_FEAT))[lane];
        u32 w2 = ((const u32*)(xb + (size_t)s2 * D_FEAT))[lane];
        u32 w3 = ((const u32*)(xb + (size_t)s3 * D_FEAT))[lane];
        u32 w4 = ((const u32*)(xb + (size_t)s4 * D_FEAT))[lane];
        u32 w5 = ((const u32*)(xb + (size_t)s5 * D_FEAT))[lane];
        u32 w6 = ((const u32*)(xb + (size_t)s6 * D_FEAT))[lane];
        u32 w7 = ((const u32*)(xb + (size_t)s7 * D_FEAT))[lane];
        a0 += bf_lo(w0); a1 += bf_hi(w0);
        b0 += bf_lo(w1); b1 += bf_hi(w1);
        c0 += bf_lo(w2); c1 += bf_hi(w2);
        d0 += bf_lo(w3); d1 += bf_hi(w3);
        e0 += bf_lo(w4); e1 += bf_hi(w4);
        f0 += bf_lo(w5); f1 += bf_hi(w5);
        g0 += bf_lo(w6); g1 += bf_hi(w6);
        h0 += bf_lo(w7); h1 += bf_hi(w7);
      }
      for (; i < e; i++) {
        int s = csr[i];
        u32 w = ((const u32*)(xb + (size_t)s * D_FEAT))[lane];
        a0 += bf_lo(w); a1 += bf_hi(w);
      }
      float s0 = ((a0 + b0) + (c0 + d0)) + ((e0 + f0) + (g0 + h0));
      float s1 = ((a1 + b1) + (c1 + d1)) + ((e1 + f1) + (g1 + h1));
      float inv = 1.0f / (float)max(e - bo, 1);
      ((u32*)(agg1 + (size_t)node * D_FEAT))[lane] = packbf(s0 * inv, s1 * inv);
    }
  }
}

// ---- kernel 2: persistent-W fused layer kernel (R6-verified, plain stores) -
__global__ __launch_bounds__(256, 2) void layer_kernel(
    const u16* __restrict__ agg1, const u16* __restrict__ xb,
    const u16* __restrict__ Wl1b, const u16* __restrict__ Wr1b,
    const float* __restrict__ bl1,
    const u16* __restrict__ Wl2b, const u16* __restrict__ Wr2b,
    const float* __restrict__ bl2,
    u16* __restrict__ p2b, float* __restrict__ r2f) {
  __shared__ u16 h_lds[16 * HLS];   // 8.4KB
  __shared__ u16 a_lds[16 * ALS];   // 4.4KB  staged agg1 tile
  __shared__ u16 x_lds[16 * ALS];   // 4.4KB  staged xb tile
  const int lane = threadIdx.x & 63;
  const int wave = threadIdx.x >> 6;      // 0..3
  const int n15  = lane & 15;
  const int quad = lane >> 4;
  const int ko   = quad * 8;
  const int colbase = wave * 64;
  const int srow = (wave << 2) + quad;     // 0..15
  const int scol = n15 * 8;                // u16 offset, 16B chunks

  short8 Bf[8][4];
  #pragma unroll
  for (int s = 0; s < 8; s++) {
    const u16* W = (s < 4) ? Wl1b : Wr1b;
    const int kk = (s & 3) * 32;
    #pragma unroll
    for (int t = 0; t < 4; t++)
      Bf[s][t] = *(const short8*)(W + (size_t)(colbase + t * 16 + n15) * D_FEAT + ko + kk);
  }

  const int  c0   = wave;
  const bool isR0 = (c0 >= 3);            // wave 3 -> r2 cols 0..15
  const int  tc0  = c0 - (isR0 ? 3 : 0);  // waves 0..2 -> p2 cols 0..47
  const int  wr0  = min(tc0 * 16 + n15, CLASSES - 1);
  const u16* Wc0  = (isR0 ? Wr2b : Wl2b) + (size_t)wr0 * HIDDEN + ko;
  const bool has1 = (wave < 2);           // waves 0,1 -> r2 cols 16..47
  const int  tc1  = wave + 1;
  const int  wr1  = min(tc1 * 16 + n15, CLASSES - 1);
  const u16* Wc1  = Wr2b + (size_t)wr1 * HIDDEN + ko;

  const float bias0 = bl2[min(tc0 * 16 + n15, CLASSES - 1)];
  const float bias1 = bl2[min(tc1 * 16 + n15, CLASSES - 1)];

  for (int tile = blockIdx.x; tile < NTILES; tile += GRID_L) {
    const int m0 = tile * 16;
    {
      const size_t g = (size_t)(m0 + srow) * D_FEAT + scol;
      *(short8*)(a_lds + srow * ALS + scol) = *(const short8*)(agg1 + g);
      *(short8*)(x_lds + srow * ALS + scol) = *(const short8*)(xb + g);
    }
    __syncthreads();
    {
      floatx4 acc[4];
      #pragma unroll
      for (int t = 0; t < 4; t++) acc[t] = floatx4{0.f, 0.f, 0.f, 0.f};

      short8 a[4];
      #pragma unroll
      for (int s = 0; s < 4; s++) a[s] = *(const short8*)(a_lds + n15 * ALS + ko + s * 32);
      #pragma unroll
      for (int s = 0; s < 4; s++)
        #pragma unroll
        for (int t = 0; t < 4; t++)
          acc[t] = __builtin_amdgcn_mfma_f32_16x16x32_bf16(a[s], Bf[s][t], acc[t], 0, 0, 0);
      #pragma unroll
      for (int s = 0; s < 4; s++) a[s] = *(const short8*)(x_lds + n15 * ALS + ko + s * 32);
      #pragma unroll
      for (int s = 0; s < 4; s++)
        #pragma unroll
        for (int t = 0; t < 4; t++)
          acc[t] = __builtin_amdgcn_mfma_f32_16x16x32_bf16(a[s], Bf[4 + s][t], acc[t], 0, 0, 0);

      #pragma unroll
      for (int t = 0; t < 4; t++) {
        int col = colbase + t * 16 + n15;
        float bias = bl1[col];
        #pragma unroll
        for (int r = 0; r < 4; r++) {
          float v = acc[t][r] + bias;
          v = v > 0.f ? v : 0.f;
          h_lds[(quad * 4 + r) * HLS + col] = f2bf(v);
        }
      }
    }
    __syncthreads();
    {
      floatx4 acc0 = floatx4{0.f, 0.f, 0.f, 0.f};
      floatx4 acc1 = floatx4{0.f, 0.f, 0.f, 0.f};
      #pragma unroll
      for (int s = 0; s < 8; s++) {
        short8 a2 = *(const short8*)(&h_lds[n15 * HLS + s * 32 + ko]);
        acc0 = __builtin_amdgcn_mfma_f32_16x16x32_bf16(a2, *(const short8*)(Wc0 + s * 32), acc0, 0, 0, 0);
        if (has1)
          acc1 = __builtin_amdgcn_mfma_f32_16x16x32_bf16(a2, *(const short8*)(Wc1 + s * 32), acc1, 0, 0, 0);
      }
      {
        int col = tc0 * 16 + n15;
        #pragma unroll
        for (int r = 0; r < 4; r++) {
          int row = m0 + quad * 4 + r;
          if (isR0) r2f[(size_t)row * R2S + col] = acc0[r] + bias0;
          else      p2b[(size_t)row * P2S + col] = f2bf(acc0[r]);
        }
      }
      if (has1) {
        int col = tc1 * 16 + n15;
        #pragma unroll
        for (int r = 0; r < 4; r++) {
          int row = m0 + quad * 4 + r;
          r2f[(size_t)row * R2S + col] = acc1[r] + bias1;
        }
      }
    }
    __syncthreads();
  }
}

// ---- kernel 3: fused mean-gather + log_softmax (R6-verified) ---------------
__global__ __launch_bounds__(256) void final_kernel(
    const u16* __restrict__ p2b, const float* __restrict__ r2f,
    const int* __restrict__ offsets, const int* __restrict__ csr_src,
    float* __restrict__ out) {
  const int node  = blockIdx.x * 4 + (threadIdx.x >> 6);
  const int lane  = threadIdx.x & 63;
  const int eslot = lane >> 5;     // which edge of the pair this half-wave owns
  const int k     = lane & 31;     // u32 column (bf16 cols 2k, 2k+1)
  const u32* p2w  = (const u32*)p2b;
  int b = offsets[node], e = offsets[node + 1];
  float slo = 0.f, shi = 0.f;
  int i = b;
  for (; i + 16 <= e; i += 16) {     // 8 slots = 16 edges
    int c[8];
    #pragma unroll
    for (int j = 0; j < 8; j++) c[j] = csr_src[i + 2 * j + eslot];
    u32 w[8];
    #pragma unroll
    for (int j = 0; j < 8; j++) w[j] = p2w[((u32)c[j] << 5) + k];
    #pragma unroll
    for (int j = 0; j < 8; j++) { slo += bf_lo(w[j]); shi += bf_hi(w[j]); }
  }
  for (; i + 2 <= e; i += 2) {
    int c = csr_src[i + eslot];
    u32 w = p2w[((u32)c << 5) + k];
    slo += bf_lo(w); shi += bf_hi(w);
  }
  if (i < e && eslot == 0) {         // odd tail: even-slot half only
    int c = csr_src[i];
    u32 w = p2w[((u32)c << 5) + k];
    slo += bf_lo(w); shi += bf_hi(w);
  }
  slo += __shfl_xor(slo, 32, 64);
  shi += __shfl_xor(shi, 32, 64);
  float vlo = __shfl(slo, lane >> 1, 64);
  float vhi = __shfl(shi, lane >> 1, 64);
  float ssum = (lane & 1) ? vhi : vlo;
  float inv = 1.0f / (float)max(e - b, 1);
  const bool act = (lane < CLASSES);
  float v = act ? (ssum * inv + r2f[(size_t)node * R2S + lane]) : -INFINITY;
  float mx = v;
  #pragma unroll
  for (int d = 1; d < 64; d <<= 1) mx = fmaxf(mx, __shfl_xor(mx, d, 64));
  float ex = act ? expf(v - mx) : 0.f;
  float sum = ex;
  #pragma unroll
  for (int d = 1; d < 64; d <<= 1) sum += __shfl_xor(sum, d, 64);
  float l = mx + logf(sum);
  if (act) out[(size_t)node * CLASSES + lane] = v - l;
}

extern "C" void kernel_launch(void* const* d_in, const int* in_sizes, int n_in,
                              void* d_out, int out_size, void* d_ws, size_t ws_size,
                              hipStream_t stream) {
  const float* x   = (const float*)d_in[0];
  const void*  ei  = d_in[1];
  const float* Wl1 = (const float*)d_in[2];
  const float* bl1 = (const float*)d_in[3];
  const float* Wr1 = (const float*)d_in[4];
  const float* Wl2 = (const float*)d_in[5];
  const float* bl2 = (const float*)d_in[6];
  const float* Wr2 = (const float*)d_in[7];

  char* ws = (char*)d_ws;
  size_t off = 0;
  int* csr       = (int*)(ws + off); off += (size_t)N_EDGES * 4;             // 3.2MB
  int* offsets   = (int*)(ws + off); off += 204800;                          // >= 50176+1 ints
  int* zctl      = (int*)(ws + off); off += 1024;                            // bcur[196]+bar[2]+steal[1]
  u32* bbuf      = (u32*)(ws + off); off += (size_t)NBUCK * BCAP * 4;        // 4.0MB
  u16* wb        = (u16*)(ws + off); off += 172288;                          // 86016 bf16 padded
  u16* xb        = (u16*)(ws + off); off += (size_t)N_NODES * D_FEAT * 2;    // 12.8MB
  u16* agg1      = (u16*)(ws + off); off += (size_t)N_NODES * D_FEAT * 2;    // 12.8MB
  u16* p2b       = (u16*)(ws + off); off += (size_t)N_NODES * P2S * 2;       // 6.4MB
  float* r2f     = (float*)(ws + off); off += (size_t)N_NODES * R2S * 4;     // 9.6MB

  u16* Wl1b = wb;
  u16* Wr1b = wb + 32768;
  u16* Wl2b = wb + 65536;
  u16* Wr2b = wb + 75776;

  hipMemsetAsync(zctl, 0, 1024, stream);
  mega_kernel<<<GRID_MEGA, 256, 0, stream>>>(x, Wl1, Wr1, Wl2, Wr2, xb, wb,
                                             ei, zctl, bbuf, offsets, csr, agg1);
  layer_kernel<<<GRID_L, 256, 0, stream>>>(agg1, xb, Wl1b, Wr1b, bl1,
                                           Wl2b, Wr2b, bl2, p2b, r2f);
  final_kernel<<<N_NODES / 4, 256, 0, stream>>>(p2b, r2f, offsets, csr, (float*)d_out);
}

// Round 10
// 279.064 us; speedup vs baseline: 3.9818x; 3.9818x over previous
//
#include <hip/hip_runtime.h>
#include <hip/hip_bf16.h>
#include <math.h>

#define N_NODES 50000
#define D_FEAT  128
#define HIDDEN  256
#define CLASSES 40
#define N_EDGES 800000
#define P2S 64   // p2 row stride (u16) -> 128B rows, gathered as 32 u32/row
#define R2S 48   // r2 row stride (f32)
#define HLS 264  // h LDS row stride in u16 (256 + 8 pad)
#define ALS 136  // A-tile LDS row stride in u16 (128 + 8 pad, keeps 16B align)
#define NTILES 3125  // 50000 / 16
#define GRID_L 512   // layer grid (2 blocks/CU at 8 waves/CU)
#define NBUCK 196    // dst buckets: bucket = dst >> 8 (256-node ranges)
#define BCAP  5120   // entries per bucket (mean 4096, sigma ~64)
#define BA_BLOCKS 784  // bucketA grid: 784*1024 = 802816 >= N_EDGES (4 edges/thread)
#define WCVT_BLOCKS 336  // 336*256 = 86016 weight elements

typedef unsigned int  u32;
typedef unsigned short u16;
typedef __attribute__((ext_vector_type(8))) short short8;
typedef __attribute__((ext_vector_type(4))) float floatx4;

__device__ __forceinline__ float bf_lo(u32 w) { union { u32 i; float f; } u; u.i = w << 16; return u.f; }
__device__ __forceinline__ float bf_hi(u32 w) { union { u32 i; float f; } u; u.i = w & 0xffff0000u; return u.f; }
__device__ __forceinline__ float bf1(u16 h)   { union { u32 i; float f; } u; u.i = ((u32)h) << 16; return u.f; }
__device__ __forceinline__ u16 f2bf(float f) {
  union { float f; u32 i; } u; u.f = f; u32 i = u.i;
  return (u16)((i + 0x7fffu + ((i >> 16) & 1u)) >> 16);  // RNE
}
__device__ __forceinline__ u32 packbf(float a, float b) { return (u32)f2bf(a) | ((u32)f2bf(b) << 16); }

// Per-block edge-dtype probe: 8 fixed samples, identical for every block.
__device__ __forceinline__ bool edges_are_i64(const void* eraw) {
  const long long* p = (const long long*)eraw;
  bool ok = true;
  #pragma unroll
  for (int i = 0; i < 8; i++) {
    long long v = p[(size_t)i * 100003];
    ok = ok && (v >= 0) && (v < N_NODES);
  }
  return ok;
}

// ---- kernel 1: x f32->bf16 + bcur zeroing (R6-verified) --------------------
__global__ __launch_bounds__(256) void cvt_x_kernel(
    const float* __restrict__ x, u16* __restrict__ xb, int* __restrict__ bcur) {
  if (blockIdx.x < 6250) {
    int i = (blockIdx.x * 256 + threadIdx.x) * 4;
    floatx4 v = *(const floatx4*)(x + i);
    u32* o = (u32*)(xb + i);
    o[0] = packbf(v.x, v.y);
    o[1] = packbf(v.z, v.w);
  } else {
    if (threadIdx.x < NBUCK) bcur[threadIdx.x] = 0;
  }
}

// ---- kernel 2: coarse bucket scatter of edges + overlapped weight cvt ------
__global__ __launch_bounds__(256) void bucketA_kernel(
    const void* __restrict__ eraw, int* __restrict__ bcur, u32* __restrict__ bbuf,
    const float* __restrict__ Wl1, const float* __restrict__ Wr1,
    const float* __restrict__ Wl2, const float* __restrict__ Wr2,
    u16* __restrict__ wb) {
  if (blockIdx.x >= BA_BLOCKS) {
    int i = (blockIdx.x - BA_BLOCKS) * 256 + threadIdx.x;
    if (i < 32768)      wb[i] = f2bf(Wl1[i]);
    else if (i < 65536) wb[i] = f2bf(Wr1[i - 32768]);
    else if (i < 75776) wb[i] = f2bf(Wl2[i - 65536]);
    else if (i < 86016) wb[i] = f2bf(Wr2[i - 75776]);
    return;
  }
  __shared__ int hist[NBUCK], base[NBUCK], loc[NBUCK];
  const bool i64f = edges_are_i64(eraw);
  const int t = threadIdx.x;
  for (int i = t; i < NBUCK; i += 256) { hist[i] = 0; loc[i] = 0; }
  __syncthreads();

  int sreg[4], dreg[4];
  const int e0 = blockIdx.x * 1024;
  #pragma unroll
  for (int j = 0; j < 4; j++) {
    int e = e0 + j * 256 + t;  // coalesced
    int ss = 0, dd = -1;
    if (e < N_EDGES) {
      if (i64f) {
        const long long* p = (const long long*)eraw;
        ss = (int)p[e]; dd = (int)p[N_EDGES + e];
      } else {
        const int* p = (const int*)eraw;
        ss = p[e]; dd = p[N_EDGES + e];
      }
      if ((u32)ss >= N_NODES || (u32)dd >= N_NODES) dd = -1;
    }
    sreg[j] = ss; dreg[j] = dd;
    if (dd >= 0) atomicAdd(&hist[dd >> 8], 1);
  }
  __syncthreads();
  for (int i = t; i < NBUCK; i += 256)
    base[i] = atomicAdd(&bcur[i], hist[i]);
  __syncthreads();
  #pragma unroll
  for (int j = 0; j < 4; j++) {
    int dd = dreg[j];
    if (dd >= 0) {
      int bk = dd >> 8;
      int pos = base[bk] + atomicAdd(&loc[bk], 1);
      if (pos < BCAP)
        bbuf[(size_t)bk * BCAP + pos] = (u32)sreg[j] | ((u32)(dd & 255) << 16);
    }
  }
}

// ---- kernel 3: fused bscan + scan2 + bucketB (R3-verified) -----------------
__global__ __launch_bounds__(256) void bucketBC_kernel(
    const u32* __restrict__ bbuf, const int* __restrict__ bcur,
    int* __restrict__ offsets, int* __restrict__ csr) {
  __shared__ int cnt[256];
  __shared__ int lds[256];
  const int t = threadIdx.x;
  const int b = blockIdx.x;
  int c196 = (t < NBUCK) ? min(bcur[t], BCAP) : 0;
  lds[t] = c196;
  __syncthreads();
  #pragma unroll
  for (int d = 1; d < 256; d <<= 1) {
    int v = (t >= d) ? lds[t - d] : 0;
    __syncthreads();
    lds[t] += v;
    __syncthreads();
  }
  const int btop = (b > 0) ? lds[b - 1] : 0;
  if (b == NBUCK - 1 && t == 0) offsets[N_NODES] = lds[NBUCK - 1];
  cnt[t] = 0;
  __syncthreads();
  const int n = min(bcur[b], BCAP);
  for (int i = t; i < n; i += 256) {
    u32 e = bbuf[(size_t)b * BCAP + i];
    atomicAdd(&cnt[(e >> 16) & 255], 1);
  }
  __syncthreads();
  int c = cnt[t];
  lds[t] = c;
  __syncthreads();
  #pragma unroll
  for (int d = 1; d < 256; d <<= 1) {
    int v = (t >= d) ? lds[t - d] : 0;
    __syncthreads();
    lds[t] += v;
    __syncthreads();
  }
  const int node = b * 256 + t;
  const int off = lds[t] - c + btop;
  if (node < N_NODES) offsets[node] = off;
  cnt[t] = off;
  __syncthreads();
  for (int i = t; i < n; i += 256) {
    u32 e = bbuf[(size_t)b * BCAP + i];
    int dl = (e >> 16) & 255;
    int pos = atomicAdd(&cnt[dl], 1);
    csr[pos] = (int)(e & 0xFFFFu);
  }
}

// ---- kernel 4: FUSED gather1 + persistent-W layer kernel -------------------
// R10: agg1 eliminated. Phase 0 of each tile computes the mean-aggregated
// rows DIRECTLY into a_lds (same 8-deep gather body, same packbf rounding
// point -> bit-identical to the old agg1 path). Saves 25.6MB of traffic and
// one dispatch; gather stalls overlap the other resident block's MFMA.
__global__ __launch_bounds__(256, 2) void layer_kernel(
    const u16* __restrict__ xb, const int* __restrict__ offsets,
    const int* __restrict__ csr,
    const u16* __restrict__ Wl1b, const u16* __restrict__ Wr1b,
    const float* __restrict__ bl1,
    const u16* __restrict__ Wl2b, const u16* __restrict__ Wr2b,
    const float* __restrict__ bl2,
    u16* __restrict__ p2b, float* __restrict__ r2f) {
  __shared__ u16 h_lds[16 * HLS];   // 8.4KB
  __shared__ u16 a_lds[16 * ALS];   // 4.4KB  gathered agg tile (computed here)
  __shared__ u16 x_lds[16 * ALS];   // 4.4KB  staged xb tile
  const int lane = threadIdx.x & 63;
  const int wave = threadIdx.x >> 6;      // 0..3
  const int n15  = lane & 15;
  const int quad = lane >> 4;
  const int ko   = quad * 8;
  const int colbase = wave * 64;
  const int srow = (wave << 2) + quad;     // 0..15
  const int scol = n15 * 8;                // u16 offset, 16B chunks

  short8 Bf[8][4];
  #pragma unroll
  for (int s = 0; s < 8; s++) {
    const u16* W = (s < 4) ? Wl1b : Wr1b;
    const int kk = (s & 3) * 32;
    #pragma unroll
    for (int t = 0; t < 4; t++)
      Bf[s][t] = *(const short8*)(W + (size_t)(colbase + t * 16 + n15) * D_FEAT + ko + kk);
  }

  const int  c0   = wave;
  const bool isR0 = (c0 >= 3);            // wave 3 -> r2 cols 0..15
  const int  tc0  = c0 - (isR0 ? 3 : 0);  // waves 0..2 -> p2 cols 0..47
  const int  wr0  = min(tc0 * 16 + n15, CLASSES - 1);
  const u16* Wc0  = (isR0 ? Wr2b : Wl2b) + (size_t)wr0 * HIDDEN + ko;
  const bool has1 = (wave < 2);           // waves 0,1 -> r2 cols 16..47
  const int  tc1  = wave + 1;
  const int  wr1  = min(tc1 * 16 + n15, CLASSES - 1);
  const u16* Wc1  = Wr2b + (size_t)wr1 * HIDDEN + ko;

  const float bias0 = bl2[min(tc0 * 16 + n15, CLASSES - 1)];
  const float bias1 = bl2[min(tc1 * 16 + n15, CLASSES - 1)];

  for (int tile = blockIdx.x; tile < NTILES; tile += GRID_L) {
    const int m0 = tile * 16;
    // ---- phase 0: stage xb tile + gather/mean 4 rows per wave into a_lds --
    {
      const size_t g = (size_t)(m0 + srow) * D_FEAT + scol;
      *(short8*)(x_lds + srow * ALS + scol) = *(const short8*)(xb + g);
    }
    for (int r = 0; r < 4; r++) {
      const int row  = (wave << 2) + r;        // 0..15
      const int node = m0 + row;
      int bo = offsets[node], e = offsets[node + 1];
      float a0 = 0.f, a1 = 0.f, b0 = 0.f, b1 = 0.f;
      float c0_ = 0.f, c1_ = 0.f, d0 = 0.f, d1 = 0.f;
      float e0 = 0.f, e1 = 0.f, f0 = 0.f, f1 = 0.f;
      float g0 = 0.f, g1 = 0.f, h0 = 0.f, h1 = 0.f;
      int i = bo;
      for (; i + 8 <= e; i += 8) {
        int s0 = csr[i],     s1 = csr[i + 1], s2 = csr[i + 2], s3 = csr[i + 3];
        int s4 = csr[i + 4], s5 = csr[i + 5], s6 = csr[i + 6], s7 = csr[i + 7];
        u32 w0 = ((const u32*)(xb + (size_t)s0 * D_FEAT))[lane];
        u32 w1 = ((const u32*)(xb + (size_t)s1 * D_FEAT))[lane];
        u32 w2 = ((const u32*)(xb + (size_t)s2 * D_FEAT))[lane];
        u32 w3 = ((const u32*)(xb + (size_t)s3 * D_FEAT))[lane];
        u32 w4 = ((const u32*)(xb + (size_t)s4 * D_FEAT))[lane];
        u32 w5 = ((const u32*)(xb + (size_t)s5 * D_FEAT))[lane];
        u32 w6 = ((const u32*)(xb + (size_t)s6 * D_FEAT))[lane];
        u32 w7 = ((const u32*)(xb + (size_t)s7 * D_FEAT))[lane];
        a0 += bf_lo(w0); a1 += bf_hi(w0);
        b0 += bf_lo(w1); b1 += bf_hi(w1);
        c0_ += bf_lo(w2); c1_ += bf_hi(w2);
        d0 += bf_lo(w3); d1 += bf_hi(w3);
        e0 += bf_lo(w4); e1 += bf_hi(w4);
        f0 += bf_lo(w5); f1 += bf_hi(w5);
        g0 += bf_lo(w6); g1 += bf_hi(w6);
        h0 += bf_lo(w7); h1 += bf_hi(w7);
      }
      for (; i < e; i++) {
        int s = csr[i];
        u32 w = ((const u32*)(xb + (size_t)s * D_FEAT))[lane];
        a0 += bf_lo(w); a1 += bf_hi(w);
      }
      float s0 = ((a0 + b0) + (c0_ + d0)) + ((e0 + f0) + (g0 + h0));
      float s1 = ((a1 + b1) + (c1_ + d1)) + ((e1 + f1) + (g1 + h1));
      float inv = 1.0f / (float)max(e - bo, 1);
      ((u32*)(a_lds + row * ALS))[lane] = packbf(s0 * inv, s1 * inv);
    }
    __syncthreads();
    // ---- phase 1: layer-1 MFMA (agg + x sides) + ReLU -> h_lds -------------
    {
      floatx4 acc[4];
      #pragma unroll
      for (int t = 0; t < 4; t++) acc[t] = floatx4{0.f, 0.f, 0.f, 0.f};

      short8 a[4];
      #pragma unroll
      for (int s = 0; s < 4; s++) a[s] = *(const short8*)(a_lds + n15 * ALS + ko + s * 32);
      #pragma unroll
      for (int s = 0; s < 4; s++)
        #pragma unroll
        for (int t = 0; t < 4; t++)
          acc[t] = __builtin_amdgcn_mfma_f32_16x16x32_bf16(a[s], Bf[s][t], acc[t], 0, 0, 0);
      #pragma unroll
      for (int s = 0; s < 4; s++) a[s] = *(const short8*)(x_lds + n15 * ALS + ko + s * 32);
      #pragma unroll
      for (int s = 0; s < 4; s++)
        #pragma unroll
        for (int t = 0; t < 4; t++)
          acc[t] = __builtin_amdgcn_mfma_f32_16x16x32_bf16(a[s], Bf[4 + s][t], acc[t], 0, 0, 0);

      #pragma unroll
      for (int t = 0; t < 4; t++) {
        int col = colbase + t * 16 + n15;
        float bias = bl1[col];
        #pragma unroll
        for (int r = 0; r < 4; r++) {
          float v = acc[t][r] + bias;
          v = v > 0.f ? v : 0.f;
          h_lds[(quad * 4 + r) * HLS + col] = f2bf(v);
        }
      }
    }
    __syncthreads();
    // ---- phase 2: layer-2 MFMA -> p2b / r2f --------------------------------
    {
      floatx4 acc0 = floatx4{0.f, 0.f, 0.f, 0.f};
      floatx4 acc1 = floatx4{0.f, 0.f, 0.f, 0.f};
      #pragma unroll
      for (int s = 0; s < 8; s++) {
        short8 a2 = *(const short8*)(&h_lds[n15 * HLS + s * 32 + ko]);
        acc0 = __builtin_amdgcn_mfma_f32_16x16x32_bf16(a2, *(const short8*)(Wc0 + s * 32), acc0, 0, 0, 0);
        if (has1)
          acc1 = __builtin_amdgcn_mfma_f32_16x16x32_bf16(a2, *(const short8*)(Wc1 + s * 32), acc1, 0, 0, 0);
      }
      {
        int col = tc0 * 16 + n15;
        #pragma unroll
        for (int r = 0; r < 4; r++) {
          int row = m0 + quad * 4 + r;
          if (isR0) r2f[(size_t)row * R2S + col] = acc0[r] + bias0;
          else      p2b[(size_t)row * P2S + col] = f2bf(acc0[r]);
        }
      }
      if (has1) {
        int col = tc1 * 16 + n15;
        #pragma unroll
        for (int r = 0; r < 4; r++) {
          int row = m0 + quad * 4 + r;
          r2f[(size_t)row * R2S + col] = acc1[r] + bias1;
        }
      }
    }
    __syncthreads();
  }
}

// ---- kernel 5: fused mean-gather + log_softmax (R6-verified) ---------------
__global__ __launch_bounds__(256) void final_kernel(
    const u16* __restrict__ p2b, const float* __restrict__ r2f,
    const int* __restrict__ offsets, const int* __restrict__ csr_src,
    float* __restrict__ out) {
  const int node  = blockIdx.x * 4 + (threadIdx.x >> 6);
  const int lane  = threadIdx.x & 63;
  const int eslot = lane >> 5;     // which edge of the pair this half-wave owns
  const int k     = lane & 31;     // u32 column (bf16 cols 2k, 2k+1)
  const u32* p2w  = (const u32*)p2b;
  int b = offsets[node], e = offsets[node + 1];
  float slo = 0.f, shi = 0.f;
  int i = b;
  for (; i + 16 <= e; i += 16) {     // 8 slots = 16 edges
    int c[8];
    #pragma unroll
    for (int j = 0; j < 8; j++) c[j] = csr_src[i + 2 * j + eslot];
    u32 w[8];
    #pragma unroll
    for (int j = 0; j < 8; j++) w[j] = p2w[((u32)c[j] << 5) + k];
    #pragma unroll
    for (int j = 0; j < 8; j++) { slo += bf_lo(w[j]); shi += bf_hi(w[j]); }
  }
  for (; i + 2 <= e; i += 2) {
    int c = csr_src[i + eslot];
    u32 w = p2w[((u32)c << 5) + k];
    slo += bf_lo(w); shi += bf_hi(w);
  }
  if (i < e && eslot == 0) {         // odd tail: even-slot half only
    int c = csr_src[i];
    u32 w = p2w[((u32)c << 5) + k];
    slo += bf_lo(w); shi += bf_hi(w);
  }
  slo += __shfl_xor(slo, 32, 64);
  shi += __shfl_xor(shi, 32, 64);
  float vlo = __shfl(slo, lane >> 1, 64);
  float vhi = __shfl(shi, lane >> 1, 64);
  float ssum = (lane & 1) ? vhi : vlo;
  float inv = 1.0f / (float)max(e - b, 1);
  const bool act = (lane < CLASSES);
  float v = act ? (ssum * inv + r2f[(size_t)node * R2S + lane]) : -INFINITY;
  float mx = v;
  #pragma unroll
  for (int d = 1; d < 64; d <<= 1) mx = fmaxf(mx, __shfl_xor(mx, d, 64));
  float ex = act ? expf(v - mx) : 0.f;
  float sum = ex;
  #pragma unroll
  for (int d = 1; d < 64; d <<= 1) sum += __shfl_xor(sum, d, 64);
  float l = mx + logf(sum);
  if (act) out[(size_t)node * CLASSES + lane] = v - l;
}

extern "C" void kernel_launch(void* const* d_in, const int* in_sizes, int n_in,
                              void* d_out, int out_size, void* d_ws, size_t ws_size,
                              hipStream_t stream) {
  const float* x   = (const float*)d_in[0];
  const void*  ei  = d_in[1];
  const float* Wl1 = (const float*)d_in[2];
  const float* bl1 = (const float*)d_in[3];
  const float* Wr1 = (const float*)d_in[4];
  const float* Wl2 = (const float*)d_in[5];
  const float* bl2 = (const float*)d_in[6];
  const float* Wr2 = (const float*)d_in[7];

  char* ws = (char*)d_ws;
  size_t off = 0;
  int* csr       = (int*)(ws + off); off += (size_t)N_EDGES * 4;             // 3.2MB
  int* offsets   = (int*)(ws + off); off += 204800;                          // >= 50176+1 ints
  int* bcur      = (int*)(ws + off); off += 1024;                            // 196 ints
  u32* bbuf      = (u32*)(ws + off); off += (size_t)NBUCK * BCAP * 4;        // 4.0MB
  u16* wb        = (u16*)(ws + off); off += 172288;                          // 86016 bf16 padded
  u16* xb        = (u16*)(ws + off); off += (size_t)N_NODES * D_FEAT * 2;    // 12.8MB
  u16* p2b       = (u16*)(ws + off); off += (size_t)N_NODES * P2S * 2;       // 6.4MB
  float* r2f     = (float*)(ws + off); off += (size_t)N_NODES * R2S * 4;     // 9.6MB

  u16* Wl1b = wb;
  u16* Wr1b = wb + 32768;
  u16* Wl2b = wb + 65536;
  u16* Wr2b = wb + 75776;

  cvt_x_kernel<<<6251, 256, 0, stream>>>(x, xb, bcur);
  bucketA_kernel<<<BA_BLOCKS + WCVT_BLOCKS, 256, 0, stream>>>(
      ei, bcur, bbuf, Wl1, Wr1, Wl2, Wr2, wb);
  bucketBC_kernel<<<NBUCK, 256, 0, stream>>>(bbuf, bcur, offsets, csr);
  layer_kernel<<<GRID_L, 256, 0, stream>>>(xb, offsets, csr, Wl1b, Wr1b, bl1,
                                           Wl2b, Wr2b, bl2, p2b, r2f);
  final_kernel<<<N_NODES / 4, 256, 0, stream>>>(p2b, r2f, offsets, csr, (float*)d_out);
}

// Round 11
// 220.687 us; speedup vs baseline: 5.0351x; 1.2645x over previous
//
#include <hip/hip_runtime.h>
#include <hip/hip_bf16.h>
#include <math.h>

#define N_NODES 50000
#define D_FEAT  128
#define HIDDEN  256
#define CLASSES 40
#define N_EDGES 800000
#define P2S 64   // p2 row stride (u16) -> 128B rows, gathered as 32 u32/row
#define R2S 48   // r2 row stride (f32)
#define HLS 264  // h LDS row stride in u16 (256 + 8 pad)
#define ALS 136  // A-tile LDS row stride in u16 (128 + 8 pad, keeps 16B align)
#define NTILES 3125  // 50000 / 16
#define GRID_L 512   // layer grid (2 blocks/CU at 8 waves/CU)
#define NBUCK 196    // dst buckets: bucket = dst >> 8 (256-node ranges)
#define BCAP  5120   // entries per bucket (mean 4096, sigma ~64)
#define XCVT_BLOCKS 6250   // x f32->bf16 chunks
#define BA_BLOCKS 784      // edge-scatter blocks: 784*1024 >= N_EDGES
#define WCVT_BLOCKS 336    // 336*256 = 86016 weight elements
#define FRONT_BLOCKS (XCVT_BLOCKS + BA_BLOCKS + WCVT_BLOCKS)  // 7370

typedef unsigned int  u32;
typedef unsigned short u16;
typedef __attribute__((ext_vector_type(8))) short short8;
typedef __attribute__((ext_vector_type(4))) float floatx4;

__device__ __forceinline__ float bf_lo(u32 w) { union { u32 i; float f; } u; u.i = w << 16; return u.f; }
__device__ __forceinline__ float bf_hi(u32 w) { union { u32 i; float f; } u; u.i = w & 0xffff0000u; return u.f; }
__device__ __forceinline__ float bf1(u16 h)   { union { u32 i; float f; } u; u.i = ((u32)h) << 16; return u.f; }
__device__ __forceinline__ u16 f2bf(float f) {
  union { float f; u32 i; } u; u.f = f; u32 i = u.i;
  return (u16)((i + 0x7fffu + ((i >> 16) & 1u)) >> 16);  // RNE
}
__device__ __forceinline__ u32 packbf(float a, float b) { return (u32)f2bf(a) | ((u32)f2bf(b) << 16); }

// Per-block edge-dtype probe: 8 fixed samples, identical for every block.
__device__ __forceinline__ bool edges_are_i64(const void* eraw) {
  const long long* p = (const long long*)eraw;
  bool ok = true;
  #pragma unroll
  for (int i = 0; i < 8; i++) {
    long long v = p[(size_t)i * 100003];
    ok = ok && (v >= 0) && (v < N_NODES);
  }
  return ok;
}

// ---- kernel 1: merged front-end: x-cvt || edge scatter || weight cvt -------
// R11: three INDEPENDENT work types as disjoint block ranges of one dispatch
// (the R2-proven wcvt-rides-bucketA pattern, extended). No sync needed;
// bcur is pre-zeroed by a tiny memset. Overlaps cvt's HBM reads with the
// edge scatter instead of serializing them across a launch boundary.
__global__ __launch_bounds__(256) void front_kernel(
    const float* __restrict__ x, u16* __restrict__ xb,
    const void* __restrict__ eraw, int* __restrict__ bcur, u32* __restrict__ bbuf,
    const float* __restrict__ Wl1, const float* __restrict__ Wr1,
    const float* __restrict__ Wl2, const float* __restrict__ Wr2,
    u16* __restrict__ wb) {
  const int t = threadIdx.x;
  if (blockIdx.x < XCVT_BLOCKS) {
    // ---- x f32 -> bf16 (R6-verified body) ----
    int i = (blockIdx.x * 256 + t) * 4;
    floatx4 v = *(const floatx4*)(x + i);
    u32* o = (u32*)(xb + i);
    o[0] = packbf(v.x, v.y);
    o[1] = packbf(v.z, v.w);
    return;
  }
  if (blockIdx.x >= XCVT_BLOCKS + BA_BLOCKS) {
    // ---- weight f32 -> bf16 (R2-verified body) ----
    int i = (blockIdx.x - XCVT_BLOCKS - BA_BLOCKS) * 256 + t;
    if (i < 32768)      wb[i] = f2bf(Wl1[i]);
    else if (i < 65536) wb[i] = f2bf(Wr1[i - 32768]);
    else if (i < 75776) wb[i] = f2bf(Wl2[i - 65536]);
    else if (i < 86016) wb[i] = f2bf(Wr2[i - 75776]);
    return;
  }
  // ---- edge coarse bucket scatter (R2-verified body) ----
  __shared__ int hist[NBUCK], base[NBUCK], loc[NBUCK];
  const bool i64f = edges_are_i64(eraw);
  const int eb = blockIdx.x - XCVT_BLOCKS;
  for (int i = t; i < NBUCK; i += 256) { hist[i] = 0; loc[i] = 0; }
  __syncthreads();

  int sreg[4], dreg[4];
  const int e0 = eb * 1024;
  #pragma unroll
  for (int j = 0; j < 4; j++) {
    int e = e0 + j * 256 + t;  // coalesced
    int ss = 0, dd = -1;
    if (e < N_EDGES) {
      if (i64f) {
        const long long* p = (const long long*)eraw;
        ss = (int)p[e]; dd = (int)p[N_EDGES + e];
      } else {
        const int* p = (const int*)eraw;
        ss = p[e]; dd = p[N_EDGES + e];
      }
      if ((u32)ss >= N_NODES || (u32)dd >= N_NODES) dd = -1;
    }
    sreg[j] = ss; dreg[j] = dd;
    if (dd >= 0) atomicAdd(&hist[dd >> 8], 1);
  }
  __syncthreads();
  for (int i = t; i < NBUCK; i += 256)
    base[i] = atomicAdd(&bcur[i], hist[i]);
  __syncthreads();
  #pragma unroll
  for (int j = 0; j < 4; j++) {
    int dd = dreg[j];
    if (dd >= 0) {
      int bk = dd >> 8;
      int pos = base[bk] + atomicAdd(&loc[bk], 1);
      if (pos < BCAP)
        bbuf[(size_t)bk * BCAP + pos] = (u32)sreg[j] | ((u32)(dd & 255) << 16);
    }
  }
}

// ---- kernel 2: fused bscan + scan2 + bucketB (R3-verified) -----------------
__global__ __launch_bounds__(256) void bucketBC_kernel(
    const u32* __restrict__ bbuf, const int* __restrict__ bcur,
    int* __restrict__ offsets, int* __restrict__ csr) {
  __shared__ int cnt[256];
  __shared__ int lds[256];
  const int t = threadIdx.x;
  const int b = blockIdx.x;
  int c196 = (t < NBUCK) ? min(bcur[t], BCAP) : 0;
  lds[t] = c196;
  __syncthreads();
  #pragma unroll
  for (int d = 1; d < 256; d <<= 1) {
    int v = (t >= d) ? lds[t - d] : 0;
    __syncthreads();
    lds[t] += v;
    __syncthreads();
  }
  const int btop = (b > 0) ? lds[b - 1] : 0;
  if (b == NBUCK - 1 && t == 0) offsets[N_NODES] = lds[NBUCK - 1];
  cnt[t] = 0;
  __syncthreads();
  const int n = min(bcur[b], BCAP);
  for (int i = t; i < n; i += 256) {
    u32 e = bbuf[(size_t)b * BCAP + i];
    atomicAdd(&cnt[(e >> 16) & 255], 1);
  }
  __syncthreads();
  int c = cnt[t];
  lds[t] = c;
  __syncthreads();
  #pragma unroll
  for (int d = 1; d < 256; d <<= 1) {
    int v = (t >= d) ? lds[t - d] : 0;
    __syncthreads();
    lds[t] += v;
    __syncthreads();
  }
  const int node = b * 256 + t;
  const int off = lds[t] - c + btop;
  if (node < N_NODES) offsets[node] = off;
  cnt[t] = off;
  __syncthreads();
  for (int i = t; i < n; i += 256) {
    u32 e = bbuf[(size_t)b * BCAP + i];
    int dl = (e >> 16) & 255;
    int pos = atomicAdd(&cnt[dl], 1);
    csr[pos] = (int)(e & 0xFFFFu);
  }
}

// ---- kernel 3: layer-1 mean aggregation, 8-way unrolled MLP (R8-verified) --
__global__ __launch_bounds__(256) void gather1_kernel(
    const u16* __restrict__ xb, const int* __restrict__ offsets,
    const int* __restrict__ csr_src, u16* __restrict__ agg1) {
  const int node = blockIdx.x * 4 + (threadIdx.x >> 6);
  const int lane = threadIdx.x & 63;
  int b = offsets[node], e = offsets[node + 1];
  float a0 = 0.f, a1 = 0.f, b0 = 0.f, b1 = 0.f;
  float c0 = 0.f, c1 = 0.f, d0 = 0.f, d1 = 0.f;
  float e0 = 0.f, e1 = 0.f, f0 = 0.f, f1 = 0.f;
  float g0 = 0.f, g1 = 0.f, h0 = 0.f, h1 = 0.f;
  int i = b;
  for (; i + 8 <= e; i += 8) {
    int s0 = csr_src[i],     s1 = csr_src[i + 1], s2 = csr_src[i + 2], s3 = csr_src[i + 3];
    int s4 = csr_src[i + 4], s5 = csr_src[i + 5], s6 = csr_src[i + 6], s7 = csr_src[i + 7];
    u32 w0 = ((const u32*)(xb + (size_t)s0 * D_FEAT))[lane];
    u32 w1 = ((const u32*)(xb + (size_t)s1 * D_FEAT))[lane];
    u32 w2 = ((const u32*)(xb + (size_t)s2 * D_FEAT))[lane];
    u32 w3 = ((const u32*)(xb + (size_t)s3 * D_FEAT))[lane];
    u32 w4 = ((const u32*)(xb + (size_t)s4 * D_FEAT))[lane];
    u32 w5 = ((const u32*)(xb + (size_t)s5 * D_FEAT))[lane];
    u32 w6 = ((const u32*)(xb + (size_t)s6 * D_FEAT))[lane];
    u32 w7 = ((const u32*)(xb + (size_t)s7 * D_FEAT))[lane];
    a0 += bf_lo(w0); a1 += bf_hi(w0);
    b0 += bf_lo(w1); b1 += bf_hi(w1);
    c0 += bf_lo(w2); c1 += bf_hi(w2);
    d0 += bf_lo(w3); d1 += bf_hi(w3);
    e0 += bf_lo(w4); e1 += bf_hi(w4);
    f0 += bf_lo(w5); f1 += bf_hi(w5);
    g0 += bf_lo(w6); g1 += bf_hi(w6);
    h0 += bf_lo(w7); h1 += bf_hi(w7);
  }
  for (; i < e; i++) {
    int s = csr_src[i];
    u32 w = ((const u32*)(xb + (size_t)s * D_FEAT))[lane];
    a0 += bf_lo(w); a1 += bf_hi(w);
  }
  float s0 = ((a0 + b0) + (c0 + d0)) + ((e0 + f0) + (g0 + h0));
  float s1 = ((a1 + b1) + (c1 + d1)) + ((e1 + f1) + (g1 + h1));
  float inv = 1.0f / (float)max(e - b, 1);
  ((u32*)(agg1 + (size_t)node * D_FEAT))[lane] = packbf(s0 * inv, s1 * inv);
}

// ---- kernel 4: persistent-W fused layer kernel (R6-verified) ---------------
__global__ __launch_bounds__(256, 2) void layer_kernel(
    const u16* __restrict__ agg1, const u16* __restrict__ xb,
    const u16* __restrict__ Wl1b, const u16* __restrict__ Wr1b,
    const float* __restrict__ bl1,
    const u16* __restrict__ Wl2b, const u16* __restrict__ Wr2b,
    const float* __restrict__ bl2,
    u16* __restrict__ p2b, float* __restrict__ r2f) {
  __shared__ u16 h_lds[16 * HLS];   // 8.4KB
  __shared__ u16 a_lds[16 * ALS];   // 4.4KB  staged agg1 tile
  __shared__ u16 x_lds[16 * ALS];   // 4.4KB  staged xb tile
  const int lane = threadIdx.x & 63;
  const int wave = threadIdx.x >> 6;      // 0..3
  const int n15  = lane & 15;
  const int quad = lane >> 4;
  const int ko   = quad * 8;
  const int colbase = wave * 64;
  const int srow = (wave << 2) + quad;     // 0..15
  const int scol = n15 * 8;                // u16 offset, 16B chunks

  short8 Bf[8][4];
  #pragma unroll
  for (int s = 0; s < 8; s++) {
    const u16* W = (s < 4) ? Wl1b : Wr1b;
    const int kk = (s & 3) * 32;
    #pragma unroll
    for (int t = 0; t < 4; t++)
      Bf[s][t] = *(const short8*)(W + (size_t)(colbase + t * 16 + n15) * D_FEAT + ko + kk);
  }

  const int  c0   = wave;
  const bool isR0 = (c0 >= 3);            // wave 3 -> r2 cols 0..15
  const int  tc0  = c0 - (isR0 ? 3 : 0);  // waves 0..2 -> p2 cols 0..47
  const int  wr0  = min(tc0 * 16 + n15, CLASSES - 1);
  const u16* Wc0  = (isR0 ? Wr2b : Wl2b) + (size_t)wr0 * HIDDEN + ko;
  const bool has1 = (wave < 2);           // waves 0,1 -> r2 cols 16..47
  const int  tc1  = wave + 1;
  const int  wr1  = min(tc1 * 16 + n15, CLASSES - 1);
  const u16* Wc1  = Wr2b + (size_t)wr1 * HIDDEN + ko;

  const float bias0 = bl2[min(tc0 * 16 + n15, CLASSES - 1)];
  const float bias1 = bl2[min(tc1 * 16 + n15, CLASSES - 1)];

  for (int tile = blockIdx.x; tile < NTILES; tile += GRID_L) {
    const int m0 = tile * 16;
    {
      const size_t g = (size_t)(m0 + srow) * D_FEAT + scol;
      *(short8*)(a_lds + srow * ALS + scol) = *(const short8*)(agg1 + g);
      *(short8*)(x_lds + srow * ALS + scol) = *(const short8*)(xb + g);
    }
    __syncthreads();
    {
      floatx4 acc[4];
      #pragma unroll
      for (int t = 0; t < 4; t++) acc[t] = floatx4{0.f, 0.f, 0.f, 0.f};

      short8 a[4];
      #pragma unroll
      for (int s = 0; s < 4; s++) a[s] = *(const short8*)(a_lds + n15 * ALS + ko + s * 32);
      #pragma unroll
      for (int s = 0; s < 4; s++)
        #pragma unroll
        for (int t = 0; t < 4; t++)
          acc[t] = __builtin_amdgcn_mfma_f32_16x16x32_bf16(a[s], Bf[s][t], acc[t], 0, 0, 0);
      #pragma unroll
      for (int s = 0; s < 4; s++) a[s] = *(const short8*)(x_lds + n15 * ALS + ko + s * 32);
      #pragma unroll
      for (int s = 0; s < 4; s++)
        #pragma unroll
        for (int t = 0; t < 4; t++)
          acc[t] = __builtin_amdgcn_mfma_f32_16x16x32_bf16(a[s], Bf[4 + s][t], acc[t], 0, 0, 0);

      #pragma unroll
      for (int t = 0; t < 4; t++) {
        int col = colbase + t * 16 + n15;
        float bias = bl1[col];
        #pragma unroll
        for (int r = 0; r < 4; r++) {
          float v = acc[t][r] + bias;
          v = v > 0.f ? v : 0.f;
          h_lds[(quad * 4 + r) * HLS + col] = f2bf(v);
        }
      }
    }
    __syncthreads();
    {
      floatx4 acc0 = floatx4{0.f, 0.f, 0.f, 0.f};
      floatx4 acc1 = floatx4{0.f, 0.f, 0.f, 0.f};
      #pragma unroll
      for (int s = 0; s < 8; s++) {
        short8 a2 = *(const short8*)(&h_lds[n15 * HLS + s * 32 + ko]);
        acc0 = __builtin_amdgcn_mfma_f32_16x16x32_bf16(a2, *(const short8*)(Wc0 + s * 32), acc0, 0, 0, 0);
        if (has1)
          acc1 = __builtin_amdgcn_mfma_f32_16x16x32_bf16(a2, *(const short8*)(Wc1 + s * 32), acc1, 0, 0, 0);
      }
      {
        int col = tc0 * 16 + n15;
        #pragma unroll
        for (int r = 0; r < 4; r++) {
          int row = m0 + quad * 4 + r;
          if (isR0) r2f[(size_t)row * R2S + col] = acc0[r] + bias0;
          else      p2b[(size_t)row * P2S + col] = f2bf(acc0[r]);
        }
      }
      if (has1) {
        int col = tc1 * 16 + n15;
        #pragma unroll
        for (int r = 0; r < 4; r++) {
          int row = m0 + quad * 4 + r;
          r2f[(size_t)row * R2S + col] = acc1[r] + bias1;
        }
      }
    }
    __syncthreads();
  }
}

// ---- kernel 5: fused mean-gather + log_softmax (R6-verified) ---------------
__global__ __launch_bounds__(256) void final_kernel(
    const u16* __restrict__ p2b, const float* __restrict__ r2f,
    const int* __restrict__ offsets, const int* __restrict__ csr_src,
    float* __restrict__ out) {
  const int node  = blockIdx.x * 4 + (threadIdx.x >> 6);
  const int lane  = threadIdx.x & 63;
  const int eslot = lane >> 5;     // which edge of the pair this half-wave owns
  const int k     = lane & 31;     // u32 column (bf16 cols 2k, 2k+1)
  const u32* p2w  = (const u32*)p2b;
  int b = offsets[node], e = offsets[node + 1];
  float slo = 0.f, shi = 0.f;
  int i = b;
  for (; i + 16 <= e; i += 16) {     // 8 slots = 16 edges
    int c[8];
    #pragma unroll
    for (int j = 0; j < 8; j++) c[j] = csr_src[i + 2 * j + eslot];
    u32 w[8];
    #pragma unroll
    for (int j = 0; j < 8; j++) w[j] = p2w[((u32)c[j] << 5) + k];
    #pragma unroll
    for (int j = 0; j < 8; j++) { slo += bf_lo(w[j]); shi += bf_hi(w[j]); }
  }
  for (; i + 2 <= e; i += 2) {
    int c = csr_src[i + eslot];
    u32 w = p2w[((u32)c << 5) + k];
    slo += bf_lo(w); shi += bf_hi(w);
  }
  if (i < e && eslot == 0) {         // odd tail: even-slot half only
    int c = csr_src[i];
    u32 w = p2w[((u32)c << 5) + k];
    slo += bf_lo(w); shi += bf_hi(w);
  }
  slo += __shfl_xor(slo, 32, 64);
  shi += __shfl_xor(shi, 32, 64);
  float vlo = __shfl(slo, lane >> 1, 64);
  float vhi = __shfl(shi, lane >> 1, 64);
  float ssum = (lane & 1) ? vhi : vlo;
  float inv = 1.0f / (float)max(e - b, 1);
  const bool act = (lane < CLASSES);
  float v = act ? (ssum * inv + r2f[(size_t)node * R2S + lane]) : -INFINITY;
  float mx = v;
  #pragma unroll
  for (int d = 1; d < 64; d <<= 1) mx = fmaxf(mx, __shfl_xor(mx, d, 64));
  float ex = act ? expf(v - mx) : 0.f;
  float sum = ex;
  #pragma unroll
  for (int d = 1; d < 64; d <<= 1) sum += __shfl_xor(sum, d, 64);
  float l = mx + logf(sum);
  if (act) out[(size_t)node * CLASSES + lane] = v - l;
}

extern "C" void kernel_launch(void* const* d_in, const int* in_sizes, int n_in,
                              void* d_out, int out_size, void* d_ws, size_t ws_size,
                              hipStream_t stream) {
  const float* x   = (const float*)d_in[0];
  const void*  ei  = d_in[1];
  const float* Wl1 = (const float*)d_in[2];
  const float* bl1 = (const float*)d_in[3];
  const float* Wr1 = (const float*)d_in[4];
  const float* Wl2 = (const float*)d_in[5];
  const float* bl2 = (const float*)d_in[6];
  const float* Wr2 = (const float*)d_in[7];

  char* ws = (char*)d_ws;
  size_t off = 0;
  int* csr       = (int*)(ws + off); off += (size_t)N_EDGES * 4;             // 3.2MB
  int* offsets   = (int*)(ws + off); off += 204800;                          // >= 50176+1 ints
  int* bcur      = (int*)(ws + off); off += 1024;                            // 196 ints
  u32* bbuf      = (u32*)(ws + off); off += (size_t)NBUCK * BCAP * 4;        // 4.0MB
  u16* wb        = (u16*)(ws + off); off += 172288;                          // 86016 bf16 padded
  u16* xb        = (u16*)(ws + off); off += (size_t)N_NODES * D_FEAT * 2;    // 12.8MB
  u16* agg1      = (u16*)(ws + off); off += (size_t)N_NODES * D_FEAT * 2;    // 12.8MB
  u16* p2b       = (u16*)(ws + off); off += (size_t)N_NODES * P2S * 2;       // 6.4MB
  float* r2f     = (float*)(ws + off); off += (size_t)N_NODES * R2S * 4;     // 9.6MB

  u16* Wl1b = wb;
  u16* Wr1b = wb + 32768;
  u16* Wl2b = wb + 65536;
  u16* Wr2b = wb + 75776;

  hipMemsetAsync(bcur, 0, NBUCK * 4, stream);
  front_kernel<<<FRONT_BLOCKS, 256, 0, stream>>>(x, xb, ei, bcur, bbuf,
                                                 Wl1, Wr1, Wl2, Wr2, wb);
  bucketBC_kernel<<<NBUCK, 256, 0, stream>>>(bbuf, bcur, offsets, csr);
  gather1_kernel<<<N_NODES / 4, 256, 0, stream>>>(xb, offsets, csr, agg1);
  layer_kernel<<<GRID_L, 256, 0, stream>>>(agg1, xb, Wl1b, Wr1b, bl1,
                                           Wl2b, Wr2b, bl2, p2b, r2f);
  final_kernel<<<N_NODES / 4, 256, 0, stream>>>(p2b, r2f, offsets, csr, (float*)d_out);
}

// Round 12
// 218.357 us; speedup vs baseline: 5.0888x; 1.0107x over previous
//
#include <hip/hip_runtime.h>
#include <hip/hip_bf16.h>
#include <math.h>

#define N_NODES 50000
#define D_FEAT  128
#define HIDDEN  256
#define CLASSES 40
#define R2S 48   // r2 row stride (f32)
#define HLS 264  // h LDS row stride in u16 (256 + 8 pad)
#define ALS 136  // A-tile LDS row stride in u16 (128 + 8 pad, keeps 16B align)
#define NTILES 3125  // 50000 / 16
#define GRID_L 512   // layer grid (2 blocks/CU at 8 waves/CU)
#define NBUCK 196    // dst buckets: bucket = dst >> 8 (256-node ranges)
#define BCAP  5120   // entries per bucket (mean 4096, sigma ~64)
#define N_EDGES 800000
#define XCVT_BLOCKS 6250   // x f32->bf16 chunks
#define BA_BLOCKS 784      // edge-scatter blocks: 784*1024 >= N_EDGES
#define WCVT_BLOCKS 336    // 336*256 = 86016 weight elements
#define FRONT_BLOCKS (XCVT_BLOCKS + BA_BLOCKS + WCVT_BLOCKS)  // 7370

typedef unsigned int  u32;
typedef unsigned short u16;
typedef __attribute__((ext_vector_type(8))) short short8;
typedef __attribute__((ext_vector_type(4))) float floatx4;

__device__ __forceinline__ float bf_lo(u32 w) { union { u32 i; float f; } u; u.i = w << 16; return u.f; }
__device__ __forceinline__ float bf_hi(u32 w) { union { u32 i; float f; } u; u.i = w & 0xffff0000u; return u.f; }
__device__ __forceinline__ float bf1(u16 h)   { union { u32 i; float f; } u; u.i = ((u32)h) << 16; return u.f; }
__device__ __forceinline__ u16 f2bf(float f) {
  union { float f; u32 i; } u; u.f = f; u32 i = u.i;
  return (u16)((i + 0x7fffu + ((i >> 16) & 1u)) >> 16);  // RNE
}
__device__ __forceinline__ u32 packbf(float a, float b) { return (u32)f2bf(a) | ((u32)f2bf(b) << 16); }

// Per-block edge-dtype probe: 8 fixed samples, identical for every block.
__device__ __forceinline__ bool edges_are_i64(const void* eraw) {
  const long long* p = (const long long*)eraw;
  bool ok = true;
  #pragma unroll
  for (int i = 0; i < 8; i++) {
    long long v = p[(size_t)i * 100003];
    ok = ok && (v >= 0) && (v < N_NODES);
  }
  return ok;
}

// ---- kernel 1: merged front-end (R11-verified): x-cvt || edges || w-cvt ----
__global__ __launch_bounds__(256) void front_kernel(
    const float* __restrict__ x, u16* __restrict__ xb,
    const void* __restrict__ eraw, int* __restrict__ bcur, u32* __restrict__ bbuf,
    const float* __restrict__ Wl1, const float* __restrict__ Wr1,
    const float* __restrict__ Wl2, const float* __restrict__ Wr2,
    u16* __restrict__ wb) {
  const int t = threadIdx.x;
  if (blockIdx.x < XCVT_BLOCKS) {
    int i = (blockIdx.x * 256 + t) * 4;
    floatx4 v = *(const floatx4*)(x + i);
    u32* o = (u32*)(xb + i);
    o[0] = packbf(v.x, v.y);
    o[1] = packbf(v.z, v.w);
    return;
  }
  if (blockIdx.x >= XCVT_BLOCKS + BA_BLOCKS) {
    int i = (blockIdx.x - XCVT_BLOCKS - BA_BLOCKS) * 256 + t;
    if (i < 32768)      wb[i] = f2bf(Wl1[i]);
    else if (i < 65536) wb[i] = f2bf(Wr1[i - 32768]);
    else if (i < 75776) wb[i] = f2bf(Wl2[i - 65536]);
    else if (i < 86016) wb[i] = f2bf(Wr2[i - 75776]);
    return;
  }
  __shared__ int hist[NBUCK], base[NBUCK], loc[NBUCK];
  const bool i64f = edges_are_i64(eraw);
  const int eb = blockIdx.x - XCVT_BLOCKS;
  for (int i = t; i < NBUCK; i += 256) { hist[i] = 0; loc[i] = 0; }
  __syncthreads();

  int sreg[4], dreg[4];
  const int e0 = eb * 1024;
  #pragma unroll
  for (int j = 0; j < 4; j++) {
    int e = e0 + j * 256 + t;  // coalesced
    int ss = 0, dd = -1;
    if (e < N_EDGES) {
      if (i64f) {
        const long long* p = (const long long*)eraw;
        ss = (int)p[e]; dd = (int)p[N_EDGES + e];
      } else {
        const int* p = (const int*)eraw;
        ss = p[e]; dd = p[N_EDGES + e];
      }
      if ((u32)ss >= N_NODES || (u32)dd >= N_NODES) dd = -1;
    }
    sreg[j] = ss; dreg[j] = dd;
    if (dd >= 0) atomicAdd(&hist[dd >> 8], 1);
  }
  __syncthreads();
  for (int i = t; i < NBUCK; i += 256)
    base[i] = atomicAdd(&bcur[i], hist[i]);
  __syncthreads();
  #pragma unroll
  for (int j = 0; j < 4; j++) {
    int dd = dreg[j];
    if (dd >= 0) {
      int bk = dd >> 8;
      int pos = base[bk] + atomicAdd(&loc[bk], 1);
      if (pos < BCAP)
        bbuf[(size_t)bk * BCAP + pos] = (u32)sreg[j] | ((u32)(dd & 255) << 16);
    }
  }
}

// ---- kernel 2: fused bscan + scan2 + bucketB (R3-verified) -----------------
__global__ __launch_bounds__(256) void bucketBC_kernel(
    const u32* __restrict__ bbuf, const int* __restrict__ bcur,
    int* __restrict__ offsets, int* __restrict__ csr) {
  __shared__ int cnt[256];
  __shared__ int lds[256];
  const int t = threadIdx.x;
  const int b = blockIdx.x;
  int c196 = (t < NBUCK) ? min(bcur[t], BCAP) : 0;
  lds[t] = c196;
  __syncthreads();
  #pragma unroll
  for (int d = 1; d < 256; d <<= 1) {
    int v = (t >= d) ? lds[t - d] : 0;
    __syncthreads();
    lds[t] += v;
    __syncthreads();
  }
  const int btop = (b > 0) ? lds[b - 1] : 0;
  if (b == NBUCK - 1 && t == 0) offsets[N_NODES] = lds[NBUCK - 1];
  cnt[t] = 0;
  __syncthreads();
  const int n = min(bcur[b], BCAP);
  for (int i = t; i < n; i += 256) {
    u32 e = bbuf[(size_t)b * BCAP + i];
    atomicAdd(&cnt[(e >> 16) & 255], 1);
  }
  __syncthreads();
  int c = cnt[t];
  lds[t] = c;
  __syncthreads();
  #pragma unroll
  for (int d = 1; d < 256; d <<= 1) {
    int v = (t >= d) ? lds[t - d] : 0;
    __syncthreads();
    lds[t] += v;
    __syncthreads();
  }
  const int node = b * 256 + t;
  const int off = lds[t] - c + btop;
  if (node < N_NODES) offsets[node] = off;
  cnt[t] = off;
  __syncthreads();
  for (int i = t; i < n; i += 256) {
    u32 e = bbuf[(size_t)b * BCAP + i];
    int dl = (e >> 16) & 255;
    int pos = atomicAdd(&cnt[dl], 1);
    csr[pos] = (int)(e & 0xFFFFu);
  }
}

// ---- kernel 3: layer-1 mean aggregation, 8-way unrolled MLP (R8-verified) --
__global__ __launch_bounds__(256) void gather1_kernel(
    const u16* __restrict__ xb, const int* __restrict__ offsets,
    const int* __restrict__ csr_src, u16* __restrict__ agg1) {
  const int node = blockIdx.x * 4 + (threadIdx.x >> 6);
  const int lane = threadIdx.x & 63;
  int b = offsets[node], e = offsets[node + 1];
  float a0 = 0.f, a1 = 0.f, b0 = 0.f, b1 = 0.f;
  float c0 = 0.f, c1 = 0.f, d0 = 0.f, d1 = 0.f;
  float e0 = 0.f, e1 = 0.f, f0 = 0.f, f1 = 0.f;
  float g0 = 0.f, g1 = 0.f, h0 = 0.f, h1 = 0.f;
  int i = b;
  for (; i + 8 <= e; i += 8) {
    int s0 = csr_src[i],     s1 = csr_src[i + 1], s2 = csr_src[i + 2], s3 = csr_src[i + 3];
    int s4 = csr_src[i + 4], s5 = csr_src[i + 5], s6 = csr_src[i + 6], s7 = csr_src[i + 7];
    u32 w0 = ((const u32*)(xb + (size_t)s0 * D_FEAT))[lane];
    u32 w1 = ((const u32*)(xb + (size_t)s1 * D_FEAT))[lane];
    u32 w2 = ((const u32*)(xb + (size_t)s2 * D_FEAT))[lane];
    u32 w3 = ((const u32*)(xb + (size_t)s3 * D_FEAT))[lane];
    u32 w4 = ((const u32*)(xb + (size_t)s4 * D_FEAT))[lane];
    u32 w5 = ((const u32*)(xb + (size_t)s5 * D_FEAT))[lane];
    u32 w6 = ((const u32*)(xb + (size_t)s6 * D_FEAT))[lane];
    u32 w7 = ((const u32*)(xb + (size_t)s7 * D_FEAT))[lane];
    a0 += bf_lo(w0); a1 += bf_hi(w0);
    b0 += bf_lo(w1); b1 += bf_hi(w1);
    c0 += bf_lo(w2); c1 += bf_hi(w2);
    d0 += bf_lo(w3); d1 += bf_hi(w3);
    e0 += bf_lo(w4); e1 += bf_hi(w4);
    f0 += bf_lo(w5); f1 += bf_hi(w5);
    g0 += bf_lo(w6); g1 += bf_hi(w6);
    h0 += bf_lo(w7); h1 += bf_hi(w7);
  }
  for (; i < e; i++) {
    int s = csr_src[i];
    u32 w = ((const u32*)(xb + (size_t)s * D_FEAT))[lane];
    a0 += bf_lo(w); a1 += bf_hi(w);
  }
  float s0 = ((a0 + b0) + (c0 + d0)) + ((e0 + f0) + (g0 + h0));
  float s1 = ((a1 + b1) + (c1 + d1)) + ((e1 + f1) + (g1 + h1));
  float inv = 1.0f / (float)max(e - b, 1);
  ((u32*)(agg1 + (size_t)node * D_FEAT))[lane] = packbf(s0 * inv, s1 * inv);
}

// ---- kernel 4: persistent-W fused layer kernel -----------------------------
// R12: p2 split restored (R3-verified write path): p2a u16[node][32] = one
// 64B line per edge-gather; p2c u16[node][8] = 800KB L2-resident side array.
__global__ __launch_bounds__(256, 2) void layer_kernel(
    const u16* __restrict__ agg1, const u16* __restrict__ xb,
    const u16* __restrict__ Wl1b, const u16* __restrict__ Wr1b,
    const float* __restrict__ bl1,
    const u16* __restrict__ Wl2b, const u16* __restrict__ Wr2b,
    const float* __restrict__ bl2,
    u16* __restrict__ p2a, u16* __restrict__ p2c, float* __restrict__ r2f) {
  __shared__ u16 h_lds[16 * HLS];   // 8.4KB
  __shared__ u16 a_lds[16 * ALS];   // 4.4KB  staged agg1 tile
  __shared__ u16 x_lds[16 * ALS];   // 4.4KB  staged xb tile
  const int lane = threadIdx.x & 63;
  const int wave = threadIdx.x >> 6;      // 0..3
  const int n15  = lane & 15;
  const int quad = lane >> 4;
  const int ko   = quad * 8;
  const int colbase = wave * 64;
  const int srow = (wave << 2) + quad;     // 0..15
  const int scol = n15 * 8;                // u16 offset, 16B chunks

  short8 Bf[8][4];
  #pragma unroll
  for (int s = 0; s < 8; s++) {
    const u16* W = (s < 4) ? Wl1b : Wr1b;
    const int kk = (s & 3) * 32;
    #pragma unroll
    for (int t = 0; t < 4; t++)
      Bf[s][t] = *(const short8*)(W + (size_t)(colbase + t * 16 + n15) * D_FEAT + ko + kk);
  }

  const int  c0   = wave;
  const bool isR0 = (c0 >= 3);            // wave 3 -> r2 cols 0..15
  const int  tc0  = c0 - (isR0 ? 3 : 0);  // waves 0..2 -> p2 cols 0..47
  const int  wr0  = min(tc0 * 16 + n15, CLASSES - 1);
  const u16* Wc0  = (isR0 ? Wr2b : Wl2b) + (size_t)wr0 * HIDDEN + ko;
  const bool has1 = (wave < 2);           // waves 0,1 -> r2 cols 16..47
  const int  tc1  = wave + 1;
  const int  wr1  = min(tc1 * 16 + n15, CLASSES - 1);
  const u16* Wc1  = Wr2b + (size_t)wr1 * HIDDEN + ko;

  const float bias0 = bl2[min(tc0 * 16 + n15, CLASSES - 1)];
  const float bias1 = bl2[min(tc1 * 16 + n15, CLASSES - 1)];

  for (int tile = blockIdx.x; tile < NTILES; tile += GRID_L) {
    const int m0 = tile * 16;
    {
      const size_t g = (size_t)(m0 + srow) * D_FEAT + scol;
      *(short8*)(a_lds + srow * ALS + scol) = *(const short8*)(agg1 + g);
      *(short8*)(x_lds + srow * ALS + scol) = *(const short8*)(xb + g);
    }
    __syncthreads();
    {
      floatx4 acc[4];
      #pragma unroll
      for (int t = 0; t < 4; t++) acc[t] = floatx4{0.f, 0.f, 0.f, 0.f};

      short8 a[4];
      #pragma unroll
      for (int s = 0; s < 4; s++) a[s] = *(const short8*)(a_lds + n15 * ALS + ko + s * 32);
      #pragma unroll
      for (int s = 0; s < 4; s++)
        #pragma unroll
        for (int t = 0; t < 4; t++)
          acc[t] = __builtin_amdgcn_mfma_f32_16x16x32_bf16(a[s], Bf[s][t], acc[t], 0, 0, 0);
      #pragma unroll
      for (int s = 0; s < 4; s++) a[s] = *(const short8*)(x_lds + n15 * ALS + ko + s * 32);
      #pragma unroll
      for (int s = 0; s < 4; s++)
        #pragma unroll
        for (int t = 0; t < 4; t++)
          acc[t] = __builtin_amdgcn_mfma_f32_16x16x32_bf16(a[s], Bf[4 + s][t], acc[t], 0, 0, 0);

      #pragma unroll
      for (int t = 0; t < 4; t++) {
        int col = colbase + t * 16 + n15;
        float bias = bl1[col];
        #pragma unroll
        for (int r = 0; r < 4; r++) {
          float v = acc[t][r] + bias;
          v = v > 0.f ? v : 0.f;
          h_lds[(quad * 4 + r) * HLS + col] = f2bf(v);
        }
      }
    }
    __syncthreads();
    {
      floatx4 acc0 = floatx4{0.f, 0.f, 0.f, 0.f};
      floatx4 acc1 = floatx4{0.f, 0.f, 0.f, 0.f};
      #pragma unroll
      for (int s = 0; s < 8; s++) {
        short8 a2 = *(const short8*)(&h_lds[n15 * HLS + s * 32 + ko]);
        acc0 = __builtin_amdgcn_mfma_f32_16x16x32_bf16(a2, *(const short8*)(Wc0 + s * 32), acc0, 0, 0, 0);
        if (has1)
          acc1 = __builtin_amdgcn_mfma_f32_16x16x32_bf16(a2, *(const short8*)(Wc1 + s * 32), acc1, 0, 0, 0);
      }
      {
        int col = tc0 * 16 + n15;
        #pragma unroll
        for (int r = 0; r < 4; r++) {
          int row = m0 + quad * 4 + r;
          if (isR0) {
            r2f[(size_t)row * R2S + col] = acc0[r] + bias0;
          } else if (col < 32) {
            p2a[(size_t)row * 32 + col] = f2bf(acc0[r]);
          } else if (col < CLASSES) {
            p2c[(size_t)row * 8 + (col - 32)] = f2bf(acc0[r]);
          }
        }
      }
      if (has1) {
        int col = tc1 * 16 + n15;
        #pragma unroll
        for (int r = 0; r < 4; r++) {
          int row = m0 + quad * 4 + r;
          r2f[(size_t)row * R2S + col] = acc1[r] + bias1;
        }
      }
    }
    __syncthreads();
  }
}

// ---- kernel 5: fused mean-gather + log_softmax -----------------------------
// R12: 4 edges per wave-slot (eslot=lane>>4, k=lane&15); p2a row = 16 u32 =
// ONE 64B line per edge; k<4 lanes also load the p2c side word (L2-hit).
// Combine groups via shfl_xor(16,32); redistribute with (lane>>1)&15.
__global__ __launch_bounds__(256) void final_kernel(
    const u16* __restrict__ p2a, const u16* __restrict__ p2c,
    const float* __restrict__ r2f,
    const int* __restrict__ offsets, const int* __restrict__ csr_src,
    float* __restrict__ out) {
  const int node  = blockIdx.x * 4 + (threadIdx.x >> 6);
  const int lane  = threadIdx.x & 63;
  const int eslot = lane >> 4;     // 0..3: which edge of the quad
  const int k     = lane & 15;     // u32 col in p2a row (bf16 cols 2k, 2k+1)
  const bool side = (k < 4);       // this lane also covers p2c word k
  const u32* pa = (const u32*)p2a; // row stride 16 u32
  const u32* pc = (const u32*)p2c; // row stride 4 u32
  int b = offsets[node], e = offsets[node + 1];
  float slo = 0.f, shi = 0.f;      // main cols 2k, 2k+1
  float tlo = 0.f, thi = 0.f;      // side cols 32+2k, 33+2k (k<4)
  int i = b;
  for (; i + 16 <= e; i += 16) {   // 4 quads = 16 edges
    int c[4];
    #pragma unroll
    for (int j = 0; j < 4; j++) c[j] = csr_src[i + 4 * j + eslot];
    u32 w[4];
    #pragma unroll
    for (int j = 0; j < 4; j++) w[j] = pa[((u32)c[j] << 4) + k];
    if (side) {
      u32 v[4];
      #pragma unroll
      for (int j = 0; j < 4; j++) v[j] = pc[((u32)c[j] << 2) + k];
      #pragma unroll
      for (int j = 0; j < 4; j++) { tlo += bf_lo(v[j]); thi += bf_hi(v[j]); }
    }
    #pragma unroll
    for (int j = 0; j < 4; j++) { slo += bf_lo(w[j]); shi += bf_hi(w[j]); }
  }
  for (; i + 4 <= e; i += 4) {     // one quad
    int c = csr_src[i + eslot];
    u32 w = pa[((u32)c << 4) + k];
    slo += bf_lo(w); shi += bf_hi(w);
    if (side) { u32 v = pc[((u32)c << 2) + k]; tlo += bf_lo(v); thi += bf_hi(v); }
  }
  if (i < e && eslot < (e - i)) {  // tail 1-3 edges: group eslot takes edge i+eslot
    int c = csr_src[i + eslot];
    u32 w = pa[((u32)c << 4) + k];
    slo += bf_lo(w); shi += bf_hi(w);
    if (side) { u32 v = pc[((u32)c << 2) + k]; tlo += bf_lo(v); thi += bf_hi(v); }
  }
  // combine the 4 edge groups (lanes k, k+16, k+32, k+48)
  slo += __shfl_xor(slo, 16, 64); slo += __shfl_xor(slo, 32, 64);
  shi += __shfl_xor(shi, 16, 64); shi += __shfl_xor(shi, 32, 64);
  tlo += __shfl_xor(tlo, 16, 64); tlo += __shfl_xor(tlo, 32, 64);
  thi += __shfl_xor(thi, 16, 64); thi += __shfl_xor(thi, 32, 64);
  // redistribute: softmax lane j needs col j
  //  j<32:  main pair k=j>>1;  32<=j<40: side pair k=(j>>1)&15 (=(j-32)>>1)
  const int src = (lane >> 1) & 15;
  float vl = __shfl(slo, src, 64);
  float vh = __shfl(shi, src, 64);
  float ul = __shfl(tlo, src, 64);
  float uh = __shfl(thi, src, 64);
  float mlo = (lane < 32) ? vl : ul;
  float mhi = (lane < 32) ? vh : uh;
  float ssum = (lane & 1) ? mhi : mlo;
  float inv = 1.0f / (float)max(e - b, 1);
  const bool act = (lane < CLASSES);
  float v = act ? (ssum * inv + r2f[(size_t)node * R2S + lane]) : -INFINITY;
  float mx = v;
  #pragma unroll
  for (int d = 1; d < 64; d <<= 1) mx = fmaxf(mx, __shfl_xor(mx, d, 64));
  float ex = act ? expf(v - mx) : 0.f;
  float sum = ex;
  #pragma unroll
  for (int d = 1; d < 64; d <<= 1) sum += __shfl_xor(sum, d, 64);
  float l = mx + logf(sum);
  if (act) out[(size_t)node * CLASSES + lane] = v - l;
}

extern "C" void kernel_launch(void* const* d_in, const int* in_sizes, int n_in,
                              void* d_out, int out_size, void* d_ws, size_t ws_size,
                              hipStream_t stream) {
  const float* x   = (const float*)d_in[0];
  const void*  ei  = d_in[1];
  const float* Wl1 = (const float*)d_in[2];
  const float* bl1 = (const float*)d_in[3];
  const float* Wr1 = (const float*)d_in[4];
  const float* Wl2 = (const float*)d_in[5];
  const float* bl2 = (const float*)d_in[6];
  const float* Wr2 = (const float*)d_in[7];

  char* ws = (char*)d_ws;
  size_t off = 0;
  int* csr       = (int*)(ws + off); off += (size_t)N_EDGES * 4;             // 3.2MB
  int* offsets   = (int*)(ws + off); off += 204800;                          // >= 50176+1 ints
  int* bcur      = (int*)(ws + off); off += 1024;                            // 196 ints
  u32* bbuf      = (u32*)(ws + off); off += (size_t)NBUCK * BCAP * 4;        // 4.0MB
  u16* wb        = (u16*)(ws + off); off += 172288;                          // 86016 bf16 padded
  u16* xb        = (u16*)(ws + off); off += (size_t)N_NODES * D_FEAT * 2;    // 12.8MB
  u16* agg1      = (u16*)(ws + off); off += (size_t)N_NODES * D_FEAT * 2;    // 12.8MB
  u16* p2a       = (u16*)(ws + off); off += (size_t)N_NODES * 32 * 2;        // 3.2MB
  u16* p2c       = (u16*)(ws + off); off += (size_t)N_NODES * 8 * 2;         // 0.8MB
  float* r2f     = (float*)(ws + off); off += (size_t)N_NODES * R2S * 4;     // 9.6MB

  u16* Wl1b = wb;
  u16* Wr1b = wb + 32768;
  u16* Wl2b = wb + 65536;
  u16* Wr2b = wb + 75776;

  hipMemsetAsync(bcur, 0, NBUCK * 4, stream);
  front_kernel<<<FRONT_BLOCKS, 256, 0, stream>>>(x, xb, ei, bcur, bbuf,
                                                 Wl1, Wr1, Wl2, Wr2, wb);
  bucketBC_kernel<<<NBUCK, 256, 0, stream>>>(bbuf, bcur, offsets, csr);
  gather1_kernel<<<N_NODES / 4, 256, 0, stream>>>(xb, offsets, csr, agg1);
  layer_kernel<<<GRID_L, 256, 0, stream>>>(agg1, xb, Wl1b, Wr1b, bl1,
                                           Wl2b, Wr2b, bl2, p2a, p2c, r2f);
  final_kernel<<<N_NODES / 4, 256, 0, stream>>>(p2a, p2c, r2f, offsets, csr, (float*)d_out);
}